// Round 7
// baseline (50.693 us; speedup 1.0000x reference)
//
#include <hip/hip_runtime.h>

#define BIGV 1.0e6f

// ---------------------------------------------------------------------------
// Kernel A: per (b, which) build a value-ascending (bucketed) candidate list.
// 16 blocks x 256 threads (4 waves). Bucket k = [k/256, (k+1)/256).
// Per-wave private counters (<=4-way contention), hierarchical shfl scan,
// per-wave private scatter offsets. Entry: uint2{ float_bits(v), i*64+j }.
// ---------------------------------------------------------------------------
__global__ __launch_bounds__(256) void build_lists(
    const float* __restrict__ gt, const float* __restrict__ pred,
    uint2* __restrict__ lists)
{
    __shared__ int cnt[4][256];   // per-wave counts -> per-wave scatter offsets
    __shared__ int wtot[4];

    const int blk   = blockIdx.x;    // 0..15
    const int b     = blk >> 1;
    const int which = blk & 1;       // 0 = pred list (m1), 1 = gt list (m2)
    const float* __restrict__ src = (which ? gt : pred) + b * 4096;
    uint2* __restrict__ out = lists + blk * 4096;

    const int tid = threadIdx.x;
    const int wv  = tid >> 6;        // wave 0..3
    const int ln  = tid & 63;

    #pragma unroll
    for (int w = 0; w < 4; ++w) cnt[w][tid] = 0;
    __syncthreads();

    // Wave wv owns values [wv*1024, wv*1024+1024), coalesced.
    float vals[16];
    int   bkt[16];
    #pragma unroll
    for (int k = 0; k < 16; ++k) {
        const int idx = wv * 1024 + k * 64 + ln;
        const float v = src[idx];
        vals[k] = v;
        int bb = (int)(v * 256.0f);
        bb = bb > 255 ? 255 : (bb < 0 ? 0 : bb);
        bkt[k] = bb;
        atomicAdd(&cnt[wv][bb], 1);
    }
    __syncthreads();

    // Exclusive prefix over bucket t = tid; wave wv scans t in [wv*64, wv*64+64).
    const int t  = tid;
    const int c0 = cnt[0][t], c1 = cnt[1][t], c2 = cnt[2][t], c3 = cnt[3][t];
    const int tot = c0 + c1 + c2 + c3;
    int incl = tot;
    #pragma unroll
    for (int s = 1; s < 64; s <<= 1) {
        int y = __shfl_up(incl, s, 64);
        if (ln >= s) incl += y;
    }
    if (ln == 63) wtot[wv] = incl;
    __syncthreads();
    int carry = 0;
    #pragma unroll
    for (int w = 0; w < 4; ++w) carry += (w < wv) ? wtot[w] : 0;
    const int P = carry + incl - tot;     // exclusive prefix of tot at bucket t
    cnt[0][t] = P;
    cnt[1][t] = P + c0;
    cnt[2][t] = P + c0 + c1;
    cnt[3][t] = P + c0 + c1 + c2;
    __syncthreads();

    #pragma unroll
    for (int k = 0; k < 16; ++k) {
        const int idx  = wv * 1024 + k * 64 + ln;
        const int slot = atomicAdd(&cnt[wv][bkt[k]], 1);   // private to wave
        out[slot] = make_uint2(__float_as_uint(vals[k]), (unsigned)idx);
    }
}

// ---------------------------------------------------------------------------
// Kernel B: one block per (b, h), 128 threads = 2 waves.
// Wave 0 walks the pred list (m1 + loss + c1), wave 1 the gt list (m2, c2).
// Candidates arrive in ascending value buckets; f = v*(1+d) >= v >= bucket
// floor, so the wave stops once all lanes have m <= floor(next). Exact.
// Last finished block (device atomic counter) finalizes d_out.
// ---------------------------------------------------------------------------
__global__ __launch_bounds__(128) void imageloss_query(
    const float* __restrict__ gt, const float* __restrict__ pred,
    const uint2* __restrict__ lists, float* __restrict__ ws,
    float* __restrict__ out)
{
    const int blk  = blockIdx.x;    // 0..511
    const int b    = blk >> 6;
    const int h    = blk & 63;
    const int tid  = threadIdx.x;
    const int w    = tid & 63;
    const int wave = tid >> 6;      // 0: pred list; 1: gt list

    const uint2* __restrict__ list = lists + (b * 2 + wave) * 4096;
    const float hf = (float)h, wf = (float)w;

    float ma = 3.4e38f, mb = 3.4e38f;   // dual accumulators for ILP
    int e = 0;
    while (true) {
        const int e_end = (e + 16 < 4096) ? e + 16 : 4096;
        for (; e < e_end; e += 2) {
            const uint2 ea = list[e];
            const uint2 eb = list[e + 1];
            const float va = __uint_as_float(ea.x);
            const float vb = __uint_as_float(eb.x);
            const int   ia = (int)ea.y, ib = (int)eb.y;
            const float dxa = hf - (float)(ia >> 6), dya = wf - (float)(ia & 63);
            const float dxb = hf - (float)(ib >> 6), dyb = wf - (float)(ib & 63);
            const float da = __builtin_amdgcn_sqrtf(fmaf(dya, dya, dxa * dxa));
            const float db = __builtin_amdgcn_sqrtf(fmaf(dyb, dyb, dxb * dxb));
            ma = fminf(ma, fmaf(va, da, va));   // v*(1+d)
            mb = fminf(mb, fmaf(vb, db, vb));
        }
        if (e >= 4096) break;
        const float vn = __uint_as_float(list[e].x);
        const float lb = floorf(vn * 256.0f) * (1.0f / 256.0f); // bucket floor
        if (__all(fminf(ma, mb) <= lb)) break;  // no lane can improve: done
    }
    const float m = fminf(ma, mb);

    const int cell = b * 4096 + h * 64 + w;
    const float g = gt[cell];
    const float p = pred[cell];

    if (wave == 0) {
        const float gth = g + (1.0f - g) * BIGV;
        float c1 = gth * m;                     // min_dist contribution
        float df = g - p;
        float sq = df * df;                     // loss contribution
        #pragma unroll
        for (int off = 32; off > 0; off >>= 1) {
            c1 += __shfl_down(c1, off, 64);
            sq += __shfl_down(sq, off, 64);
        }
        if (w == 0) {
            atomicAdd(&ws[0], sq);
            atomicAdd(&ws[1], c1);
        }
    } else {
        const float pth = p + (1.0f - p) * BIGV;
        float c2 = pth * m;                     // min_dist_inv contribution
        #pragma unroll
        for (int off = 32; off > 0; off >>= 1)
            c2 += __shfl_down(c2, off, 64);
        if (w == 0) atomicAdd(&ws[2], c2);
    }

    __syncthreads();
    if (tid == 0) {
        __threadfence();                        // make this block's adds visible
        const int old = atomicAdd((int*)&ws[3], 1);   // ws[3]: int counter (memset 0)
        if (old == 511) {                       // last block: finalize
            const float s0 = atomicAdd(&ws[0], 0.0f); // coherent (device-scope) reads
            const float s1 = atomicAdd(&ws[1], 0.0f);
            const float s2 = atomicAdd(&ws[2], 0.0f);
            out[0] = s0 * (1.0f / 512.0f);
            out[1] = s1 * (1.0f / 32768.0f);
            out[2] = s2 * (1.0f / 32768.0f);
        }
    }
}

extern "C" void kernel_launch(void* const* d_in, const int* in_sizes, int n_in,
                              void* d_out, int out_size, void* d_ws, size_t ws_size,
                              hipStream_t stream)
{
    const float* gt   = (const float*)d_in[0];
    const float* pred = (const float*)d_in[1];
    float* out = (float*)d_out;
    float* ws  = (float*)d_ws;
    uint2* lists = (uint2*)((char*)d_ws + 1024);   // 16 lists x 4096 x 8 B

    hipMemsetAsync(ws, 0, 4 * sizeof(float), stream);   // ws[0..2] sums, ws[3] counter
    build_lists<<<16, 256, 0, stream>>>(gt, pred, lists);
    imageloss_query<<<512, 128, 0, stream>>>(gt, pred, lists, ws, out);
}

// Round 8
// 45.824 us; speedup vs baseline: 1.1063x; 1.1063x over previous
//
#include <hip/hip_runtime.h>

#define BIGV 1.0e6f

// ---------------------------------------------------------------------------
// Kernel A: per (b, which) build a value-ascending (bucketed) candidate list.
// 16 blocks x 256 threads (4 waves). Bucket k = [k/256, (k+1)/256).
// Per-wave private counters, hierarchical shfl scan, per-wave scatter offsets.
// Entry: uint2{ float_bits(v), i*64+j }. Ascending bucket order.
// ---------------------------------------------------------------------------
__global__ __launch_bounds__(256) void build_lists(
    const float* __restrict__ gt, const float* __restrict__ pred,
    uint2* __restrict__ lists)
{
    __shared__ int cnt[4][256];
    __shared__ int wtot[4];

    const int blk   = blockIdx.x;    // 0..15
    const int b     = blk >> 1;
    const int which = blk & 1;       // 0 = pred list (m1), 1 = gt list (m2)
    const float* __restrict__ src = (which ? gt : pred) + b * 4096;
    uint2* __restrict__ out = lists + blk * 4096;

    const int tid = threadIdx.x;
    const int wv  = tid >> 6;
    const int ln  = tid & 63;

    #pragma unroll
    for (int w = 0; w < 4; ++w) cnt[w][tid] = 0;
    __syncthreads();

    float vals[16];
    int   bkt[16];
    #pragma unroll
    for (int k = 0; k < 16; ++k) {
        const int idx = wv * 1024 + k * 64 + ln;
        const float v = src[idx];
        vals[k] = v;
        int bb = (int)(v * 256.0f);
        bb = bb > 255 ? 255 : (bb < 0 ? 0 : bb);
        bkt[k] = bb;
        atomicAdd(&cnt[wv][bb], 1);
    }
    __syncthreads();

    const int t  = tid;
    const int c0 = cnt[0][t], c1 = cnt[1][t], c2 = cnt[2][t], c3 = cnt[3][t];
    const int tot = c0 + c1 + c2 + c3;
    int incl = tot;
    #pragma unroll
    for (int s = 1; s < 64; s <<= 1) {
        int y = __shfl_up(incl, s, 64);
        if (ln >= s) incl += y;
    }
    if (ln == 63) wtot[wv] = incl;
    __syncthreads();
    int carry = 0;
    #pragma unroll
    for (int w = 0; w < 4; ++w) carry += (w < wv) ? wtot[w] : 0;
    const int P = carry + incl - tot;
    cnt[0][t] = P;
    cnt[1][t] = P + c0;
    cnt[2][t] = P + c0 + c1;
    cnt[3][t] = P + c0 + c1 + c2;
    __syncthreads();

    #pragma unroll
    for (int k = 0; k < 16; ++k) {
        const int idx  = wv * 1024 + k * 64 + ln;
        const int slot = atomicAdd(&cnt[wv][bkt[k]], 1);
        out[slot] = make_uint2(__float_as_uint(vals[k]), (unsigned)idx);
    }
}

// Process 2 entries packed in one uint4 (wave-uniform registers).
#define ENTRY2(Q)                                                          \
    {                                                                      \
        const float va = __uint_as_float((Q).x);                           \
        const int   ia = (int)(Q).y;                                       \
        const float vb = __uint_as_float((Q).z);                           \
        const int   ib = (int)(Q).w;                                       \
        const float dxa = hf - (float)(ia >> 6);                           \
        const float dya = wf - (float)(ia & 63);                           \
        const float dxb = hf - (float)(ib >> 6);                           \
        const float dyb = wf - (float)(ib & 63);                           \
        const float da = __builtin_amdgcn_sqrtf(fmaf(dya, dya, dxa * dxa));\
        const float db = __builtin_amdgcn_sqrtf(fmaf(dyb, dyb, dxb * dxb));\
        ma = fminf(ma, fmaf(va, da, va));                                  \
        mb = fminf(mb, fmaf(vb, db, vb));                                  \
    }

// ---------------------------------------------------------------------------
// Kernel B: one block per (b, h), 128 threads = 2 waves.
// Wave 0 walks the pred list (m1 + loss + c1), wave 1 the gt list (m2, c2).
// 16-entry register chunks, software-prefetched; termination bound from the
// CURRENT chunk's last value (all later entries are in >= its bucket, so
// v >= floor(vlast*256)/256) -- exact, and keeps prefetch off the critical
// path. Last finished block finalizes d_out.
// ---------------------------------------------------------------------------
__global__ __launch_bounds__(128) void imageloss_query(
    const float* __restrict__ gt, const float* __restrict__ pred,
    const uint2* __restrict__ lists, float* __restrict__ ws,
    float* __restrict__ out)
{
    const int blk  = blockIdx.x;    // 0..511
    const int b    = blk >> 6;
    const int h    = blk & 63;
    const int tid  = threadIdx.x;
    const int w    = tid & 63;
    const int wave = tid >> 6;      // 0: pred list; 1: gt list

    const uint4* __restrict__ lp4 =
        (const uint4*)(lists + (b * 2 + wave) * 4096);   // 2 entries per uint4
    const float hf = (float)h, wf = (float)w;

    float ma = 3.4e38f, mb = 3.4e38f;

    uint4 Ca0, Ca1, Ca2, Ca3, Ca4, Ca5, Ca6, Ca7;
    uint4 Cb0, Cb1, Cb2, Cb3, Cb4, Cb5, Cb6, Cb7;

    // Prologue: load chunk 0 (entries 0..15 = uint4 0..7).
    Ca0 = lp4[0]; Ca1 = lp4[1]; Ca2 = lp4[2]; Ca3 = lp4[3];
    Ca4 = lp4[4]; Ca5 = lp4[5]; Ca6 = lp4[6]; Ca7 = lp4[7];

    int e = 0;                       // entry index of current chunk start
    while (true) {
        // Prefetch next chunk before computing (loads overlap compute).
        const int q0 = (e >> 1) + 8;
        const bool have_next = (e + 16 < 4096);
        if (have_next) {
            Cb0 = lp4[q0 + 0]; Cb1 = lp4[q0 + 1];
            Cb2 = lp4[q0 + 2]; Cb3 = lp4[q0 + 3];
            Cb4 = lp4[q0 + 4]; Cb5 = lp4[q0 + 5];
            Cb6 = lp4[q0 + 6]; Cb7 = lp4[q0 + 7];
        }

        ENTRY2(Ca0) ENTRY2(Ca1) ENTRY2(Ca2) ENTRY2(Ca3)
        ENTRY2(Ca4) ENTRY2(Ca5) ENTRY2(Ca6) ENTRY2(Ca7)

        e += 16;
        if (e >= 4096) break;

        // Sound bound: every entry at position >= e is in a bucket >= the
        // bucket of entry e-1, hence v >= floor(vlast*256)/256.
        const float vlast = __uint_as_float(Ca7.z);
        const float lb = floorf(vlast * 256.0f) * (1.0f / 256.0f);
        if (__all(fminf(ma, mb) <= lb)) break;

        Ca0 = Cb0; Ca1 = Cb1; Ca2 = Cb2; Ca3 = Cb3;
        Ca4 = Cb4; Ca5 = Cb5; Ca6 = Cb6; Ca7 = Cb7;
    }
    const float m = fminf(ma, mb);

    const int cell = b * 4096 + h * 64 + w;
    const float g = gt[cell];
    const float p = pred[cell];

    if (wave == 0) {
        const float gth = g + (1.0f - g) * BIGV;
        float c1 = gth * m;                     // min_dist contribution
        float df = g - p;
        float sq = df * df;                     // loss contribution
        #pragma unroll
        for (int off = 32; off > 0; off >>= 1) {
            c1 += __shfl_down(c1, off, 64);
            sq += __shfl_down(sq, off, 64);
        }
        if (w == 0) {
            atomicAdd(&ws[0], sq);
            atomicAdd(&ws[1], c1);
        }
    } else {
        const float pth = p + (1.0f - p) * BIGV;
        float c2 = pth * m;                     // min_dist_inv contribution
        #pragma unroll
        for (int off = 32; off > 0; off >>= 1)
            c2 += __shfl_down(c2, off, 64);
        if (w == 0) atomicAdd(&ws[2], c2);
    }

    __syncthreads();
    if (tid == 0) {
        __threadfence();
        const int old = atomicAdd((int*)&ws[3], 1);   // ws[3]: counter (memset 0)
        if (old == 511) {
            const float s0 = atomicAdd(&ws[0], 0.0f); // device-scope coherent reads
            const float s1 = atomicAdd(&ws[1], 0.0f);
            const float s2 = atomicAdd(&ws[2], 0.0f);
            out[0] = s0 * (1.0f / 512.0f);
            out[1] = s1 * (1.0f / 32768.0f);
            out[2] = s2 * (1.0f / 32768.0f);
        }
    }
}

extern "C" void kernel_launch(void* const* d_in, const int* in_sizes, int n_in,
                              void* d_out, int out_size, void* d_ws, size_t ws_size,
                              hipStream_t stream)
{
    const float* gt   = (const float*)d_in[0];
    const float* pred = (const float*)d_in[1];
    float* out = (float*)d_out;
    float* ws  = (float*)d_ws;
    uint2* lists = (uint2*)((char*)d_ws + 1024);   // 16 lists x 4096 x 8 B

    hipMemsetAsync(ws, 0, 4 * sizeof(float), stream);   // sums + counter
    build_lists<<<16, 256, 0, stream>>>(gt, pred, lists);
    imageloss_query<<<512, 128, 0, stream>>>(gt, pred, lists, ws, out);
}